// Round 7
// baseline (650.390 us; speedup 1.0000x reference)
//
#include <hip/hip_runtime.h>
#include <math.h>

// SwinMLP block.
//   kprep: split fc1/fc2 weights into bf16 hi/lo, packed in MFMA B-frag lane order (d_ws)
//   ka   : LN1 + windowed spatial MLP-mix + residual (fp32)        -> d_out = x2
//   kb   : LN2 + fc1 + exact GELU + fc2 + residual, bf16x3 MFMA    -> d_out in place
//   kb_f32: fallback (no scratch needed) if ws_size < 512 KB.
// Geometry: H=W=56, C=128, NH=4, WS=7, PAD=4 -> padded 63x63 = 9x9 windows.

#define HH      56
#define WWID    56
#define CC      128
#define NHEAD   4
#define WS7     7
#define PAD4    4
#define NW      9
#define AREA    49
#define BATCH   64
#define LTOK    3136
#define HIDDEN  512
#define EPSF    1e-5f

typedef float f32x4 __attribute__((ext_vector_type(4)));
typedef float f32x2 __attribute__((ext_vector_type(2)));
typedef short s16x8 __attribute__((ext_vector_type(8)));

__device__ __forceinline__ unsigned short f2bf(float x) {
    union { float f; unsigned int u; } c; c.f = x;
    return (unsigned short)((c.u + 0x7FFFu + ((c.u >> 16) & 1u)) >> 16);
}
__device__ __forceinline__ float bf2f(unsigned short h) {
    union { float f; unsigned int u; } c; c.u = ((unsigned int)h) << 16;
    return c.f;
}

// ---------------- weight prep: fp32 -> bf16 hi/lo, MFMA-fragment packed ----------------
// wp1[split][nf(32)][ks(4)][lane(64)][8]  <- w1[nf*16+(l&15)][ks*32+8*(l>>4)+j]
// wp2[split][cf(8)][ks(16)][lane(64)][8]  <- w2[cf*16+(l&15)][ks*32+8*(l>>4)+j]
__global__ __launch_bounds__(256) void kprep(const float* __restrict__ w1,
                                             const float* __restrict__ w2,
                                             unsigned short* __restrict__ wp1,
                                             unsigned short* __restrict__ wp2) {
    const int t = blockIdx.x * 256 + threadIdx.x;   // 0..16383
    const int lane = t & 63;
    const int grp = t >> 6;                          // 0..255
    const float* src;
    unsigned short* dhi;
    if (grp < 128) {
        const int nf = grp >> 2, ks = grp & 3;
        src = w1 + (size_t)(nf * 16 + (lane & 15)) * CC + ks * 32 + 8 * (lane >> 4);
        dhi = wp1 + (size_t)grp * 512 + lane * 8;
    } else {
        const int g2 = grp - 128;
        const int cf = g2 >> 4, ks = g2 & 15;
        src = w2 + (size_t)(cf * 16 + (lane & 15)) * HIDDEN + ks * 32 + 8 * (lane >> 4);
        dhi = wp2 + (size_t)g2 * 512 + lane * 8;
    }
    const f32x4 a = *(const f32x4*)src;
    const f32x4 b = *(const f32x4*)(src + 4);
    const float v[8] = {a[0], a[1], a[2], a[3], b[0], b[1], b[2], b[3]};
    s16x8 H, L;
    #pragma unroll
    for (int j = 0; j < 8; j++) {
        const unsigned short h = f2bf(v[j]);
        H[j] = (short)h;
        L[j] = (short)f2bf(v[j] - bf2f(h));
    }
    *(s16x8*)dhi = H;
    *(s16x8*)(dhi + 65536) = L;   // lo split lives 65536 shorts later
}

// ---------------- Kernel A: LN1 + spatial mix + residual (fp32) ----------------
__global__ __launch_bounds__(256) void ka_ln_spatial(
    const float* __restrict__ x,
    const float* __restrict__ gamma1, const float* __restrict__ beta1,
    const float* __restrict__ sw, const float* __restrict__ sb,
    float* __restrict__ x2)
{
    __shared__ float xn_s[AREA][CC];
    __shared__ float w_s[NHEAD * AREA * AREA];
    __shared__ float b_s[NHEAD * AREA];

    const int tid = threadIdx.x;
    const int blk = blockIdx.x;
    const int b   = blk / (NW * NW);
    const int wr  = blk % (NW * NW);
    const int wh  = wr / NW, ww = wr % NW;
    const int row0 = wh * WS7 - PAD4;
    const int col0 = ww * WS7 - PAD4;

    // stage spatial weights, vectorized (2401 f32x4 = 9604 floats)
    for (int i = tid; i < (NHEAD * AREA * AREA) / 4; i += 256)
        *(f32x4*)&w_s[4 * i] = *(const f32x4*)(sw + 4 * i);
    if (tid < NHEAD * AREA) b_s[tid] = sb[tid];

    const int wave = tid >> 6, lane = tid & 63;
    const f32x2 gg = *(const f32x2*)(gamma1 + 2 * lane);
    const f32x2 bb = *(const f32x2*)(beta1  + 2 * lane);
    for (int p = wave; p < AREA; p += 4) {
        const int r  = row0 + p / 7;
        const int cl = col0 + p % 7;
        const bool valid = (r >= 0) && (r < HH) && (cl >= 0) && (cl < WWID);
        f32x2 v = {0.f, 0.f};
        if (valid)
            v = *(const f32x2*)(x + ((size_t)b * LTOK + r * WWID + cl) * CC + 2 * lane);
        float s  = v[0] + v[1];
        float sq = v[0] * v[0] + v[1] * v[1];
        #pragma unroll
        for (int m = 1; m < 64; m <<= 1) {
            s  += __shfl_xor(s,  m);
            sq += __shfl_xor(sq, m);
        }
        const float mu   = s * (1.f / CC);
        const float rstd = rsqrtf(sq * (1.f / CC) - mu * mu + EPSF);
        f32x2 o;
        o[0] = valid ? (v[0] - mu) * rstd * gg[0] + bb[0] : 0.f;
        o[1] = valid ? (v[1] - mu) * rstd * gg[1] + bb[1] : 0.f;
        *(f32x2*)&xn_s[p][2 * lane] = o;
    }
    __syncthreads();

    const int cg = tid & 31, lg = tid >> 5;
    const int c = 4 * cg, g = cg >> 3;
    float acc[7][4];
    int lv[7];
    #pragma unroll
    for (int i = 0; i < 7; i++) {
        const int l = lg + 8 * i;
        lv[i] = (l < AREA) ? l : -1;
        const float bias = b_s[g * AREA + (lv[i] < 0 ? 0 : lv[i])];
        #pragma unroll
        for (int q = 0; q < 4; q++) acc[i][q] = bias;
    }
    for (int k = 0; k < AREA; ++k) {
        const f32x4 xv = *(const f32x4*)&xn_s[k][c];
        #pragma unroll
        for (int i = 0; i < 7; i++) {
            const int l = lv[i] < 0 ? 0 : lv[i];
            const float wv = w_s[(g * AREA + l) * AREA + k];
            #pragma unroll
            for (int q = 0; q < 4; q++) acc[i][q] += wv * xv[q];
        }
    }
    #pragma unroll
    for (int i = 0; i < 7; i++) {
        if (lv[i] < 0) continue;
        const int l  = lv[i];
        const int r  = row0 + l / 7;
        const int cl = col0 + l % 7;
        if (r < 0 || r >= HH || cl < 0 || cl >= WWID) continue;
        const size_t idx = ((size_t)b * LTOK + r * WWID + cl) * CC + c;
        const f32x4 rx = *(const f32x4*)(x + idx);
        f32x4 o;
        #pragma unroll
        for (int q = 0; q < 4; q++) o[q] = rx[q] + acc[i][q];
        *(f32x4*)(x2 + idx) = o;
    }
}

// ---------------- Kernel B: LN2 + MLP via bf16x3-split MFMA ----------------
// 64 tokens/block, 4 hidden chunks of 128. GEMM2 computed transposed
// (M=channels, N=tokens) so epilogue stores are contiguous f32x4 per lane.
// LDS rows XOR-swizzled: short-index ch ^ ((row&7)*8)  (== byte ^ ((row&7)<<4)).
__global__ __launch_bounds__(256, 2) void kb_ln_mlp_mfma(
    float* __restrict__ xio,
    const float* __restrict__ gamma2, const float* __restrict__ beta2,
    const float* __restrict__ fb1, const float* __restrict__ fb2,
    const unsigned short* __restrict__ wp1, const unsigned short* __restrict__ wp2)
{
    __shared__ __attribute__((aligned(16))) unsigned short xnh[64 * CC];
    __shared__ __attribute__((aligned(16))) unsigned short xnl[64 * CC];
    __shared__ __attribute__((aligned(16))) unsigned short gshh[64 * CC];
    __shared__ __attribute__((aligned(16))) unsigned short gshl[64 * CC];

    const int tid  = threadIdx.x;
    const int wave = tid >> 6, lane = tid & 63;
    const int l15  = lane & 15, l4 = lane >> 4;
    const size_t tok0 = (size_t)blockIdx.x * 64;

    // ---- LN2 -> bf16 hi/lo in LDS ----
    {
        const f32x2 gg = *(const f32x2*)(gamma2 + 2 * lane);
        const f32x2 bb = *(const f32x2*)(beta2  + 2 * lane);
        for (int tt = wave; tt < 64; tt += 4) {
            const f32x2 v = *(const f32x2*)(xio + (tok0 + tt) * CC + 2 * lane);
            float s  = v[0] + v[1];
            float sq = v[0] * v[0] + v[1] * v[1];
            #pragma unroll
            for (int m = 1; m < 64; m <<= 1) {
                s  += __shfl_xor(s,  m);
                sq += __shfl_xor(sq, m);
            }
            const float mu   = s * (1.f / CC);
            const float rstd = rsqrtf(sq * (1.f / CC) - mu * mu + EPSF);
            const float o0 = (v[0] - mu) * rstd * gg[0] + bb[0];
            const float o1 = (v[1] - mu) * rstd * gg[1] + bb[1];
            const unsigned short h0 = f2bf(o0), h1 = f2bf(o1);
            const unsigned short q0 = f2bf(o0 - bf2f(h0)), q1 = f2bf(o1 - bf2f(h1));
            const int sbase = tt * CC + ((2 * lane) ^ ((tt & 7) * 8));
            *(unsigned int*)&xnh[sbase] = (unsigned int)h0 | ((unsigned int)h1 << 16);
            *(unsigned int*)&xnl[sbase] = (unsigned int)q0 | ((unsigned int)q1 << 16);
        }
    }
    __syncthreads();

    f32x4 acc2[2][4];
    #pragma unroll
    for (int i = 0; i < 2; i++)
        #pragma unroll
        for (int j = 0; j < 4; j++) acc2[i][j] = {0.f, 0.f, 0.f, 0.f};

    for (int ci = 0; ci < 4; ++ci) {
        // ---- GEMM1 chunk: (64 tok x 128 hid), K=128; wave n-split of 32 ----
        f32x4 acc1[4][2];
        #pragma unroll
        for (int i = 0; i < 4; i++)
            #pragma unroll
            for (int j = 0; j < 2; j++) acc1[i][j] = {0.f, 0.f, 0.f, 0.f};

        for (int ks = 0; ks < 4; ++ks) {
            s16x8 ah[4], al[4];
            #pragma unroll
            for (int m = 0; m < 4; ++m) {
                const int row  = m * 16 + l15;
                const int sidx = row * CC + ((ks * 32 + 8 * l4) ^ ((row & 7) * 8));
                ah[m] = *(const s16x8*)&xnh[sidx];
                al[m] = *(const s16x8*)&xnl[sidx];
            }
            s16x8 bh[2], bl[2];
            #pragma unroll
            for (int n = 0; n < 2; ++n) {
                const int nf = ci * 8 + wave * 2 + n;
                const unsigned short* p = wp1 + (size_t)(nf * 4 + ks) * 512 + lane * 8;
                bh[n] = *(const s16x8*)p;
                bl[n] = *(const s16x8*)(p + 65536);
            }
            #pragma unroll
            for (int m = 0; m < 4; ++m)
                #pragma unroll
                for (int n = 0; n < 2; ++n) {
                    acc1[m][n] = __builtin_amdgcn_mfma_f32_16x16x32_bf16(ah[m], bh[n], acc1[m][n], 0, 0, 0);
                    acc1[m][n] = __builtin_amdgcn_mfma_f32_16x16x32_bf16(ah[m], bl[n], acc1[m][n], 0, 0, 0);
                    acc1[m][n] = __builtin_amdgcn_mfma_f32_16x16x32_bf16(al[m], bh[n], acc1[m][n], 0, 0, 0);
                }
        }
        // ---- bias + exact GELU -> gsh (bf16 hi/lo, swizzled) ----
        #pragma unroll
        for (int n = 0; n < 2; ++n) {
            const int hloc = wave * 32 + n * 16 + l15;
            const float bias = fb1[ci * 128 + hloc];
            #pragma unroll
            for (int m = 0; m < 4; ++m) {
                #pragma unroll
                for (int r = 0; r < 4; ++r) {
                    const float u  = acc1[m][n][r] + bias;
                    const float ge = 0.5f * u * (1.f + erff(u * 0.70710678118654752f));
                    const unsigned short gh = f2bf(ge);
                    const unsigned short gl = f2bf(ge - bf2f(gh));
                    const int tokr = m * 16 + l4 * 4 + r;
                    const int sidx = tokr * CC + (hloc ^ ((tokr & 7) * 8));
                    gshh[sidx] = gh;
                    gshl[sidx] = gl;
                }
            }
        }
        __syncthreads();
        // ---- GEMM2 partial (transposed): C[ch=128][tok=64] += W2c . g^T ----
        for (int ks = 0; ks < 4; ++ks) {
            s16x8 wh2[2], wl2[2];
            #pragma unroll
            for (int mf = 0; mf < 2; ++mf) {
                const int cf = wave * 2 + mf;
                const unsigned short* p = wp2 + (size_t)(cf * 16 + ci * 4 + ks) * 512 + lane * 8;
                wh2[mf] = *(const s16x8*)p;
                wl2[mf] = *(const s16x8*)(p + 65536);
            }
            s16x8 gh[4], gl[4];
            #pragma unroll
            for (int nt = 0; nt < 4; ++nt) {
                const int row  = nt * 16 + l15;
                const int sidx = row * CC + ((ks * 32 + 8 * l4) ^ ((row & 7) * 8));
                gh[nt] = *(const s16x8*)&gshh[sidx];
                gl[nt] = *(const s16x8*)&gshl[sidx];
            }
            #pragma unroll
            for (int mf = 0; mf < 2; ++mf)
                #pragma unroll
                for (int nt = 0; nt < 4; ++nt) {
                    acc2[mf][nt] = __builtin_amdgcn_mfma_f32_16x16x32_bf16(wh2[mf], gh[nt], acc2[mf][nt], 0, 0, 0);
                    acc2[mf][nt] = __builtin_amdgcn_mfma_f32_16x16x32_bf16(wh2[mf], gl[nt], acc2[mf][nt], 0, 0, 0);
                    acc2[mf][nt] = __builtin_amdgcn_mfma_f32_16x16x32_bf16(wl2[mf], gh[nt], acc2[mf][nt], 0, 0, 0);
                }
        }
        __syncthreads();   // gsh reused next chunk
    }

    // ---- epilogue: out = x2 + fc2 + bias (in place, contiguous f32x4/lane) ----
    #pragma unroll
    for (int mf = 0; mf < 2; ++mf) {
        const int ch = wave * 32 + mf * 16 + l4 * 4;
        const f32x4 bz = *(const f32x4*)(fb2 + ch);
        #pragma unroll
        for (int nt = 0; nt < 4; ++nt) {
            const size_t idx = (tok0 + nt * 16 + l15) * CC + ch;
            const f32x4 xv = *(const f32x4*)(xio + idx);
            f32x4 o;
            #pragma unroll
            for (int r = 0; r < 4; ++r) o[r] = xv[r] + acc2[mf][nt][r] + bz[r];
            *(f32x4*)(xio + idx) = o;
        }
    }
}

// ---------------- Kernel B fallback: fp32 VALU path (no scratch) ----------------
__global__ __launch_bounds__(256) void kb_ln_mlp_f32(
    float* __restrict__ xio,
    const float* __restrict__ gamma2, const float* __restrict__ beta2,
    const float* __restrict__ w1, const float* __restrict__ fb1,
    const float* __restrict__ w2, const float* __restrict__ fb2)
{
    __shared__ float xn[64][CC];
    __shared__ float gsh[64][64];
    __shared__ float wsh[CC * 64];

    const int tid = threadIdx.x;
    const size_t tok0 = (size_t)blockIdx.x * 64;
    const int wave = tid >> 6, lane = tid & 63;

    {
        const f32x2 gg = *(const f32x2*)(gamma2 + 2 * lane);
        const f32x2 bb = *(const f32x2*)(beta2  + 2 * lane);
        for (int t = wave; t < 64; t += 4) {
            const f32x2 v = *(const f32x2*)(xio + (tok0 + t) * CC + 2 * lane);
            float s  = v[0] + v[1];
            float sq = v[0] * v[0] + v[1] * v[1];
            #pragma unroll
            for (int m = 1; m < 64; m <<= 1) {
                s  += __shfl_xor(s,  m);
                sq += __shfl_xor(sq, m);
            }
            const float mu   = s * (1.f / CC);
            const float rstd = rsqrtf(sq * (1.f / CC) - mu * mu + EPSF);
            f32x2 o;
            o[0] = (v[0] - mu) * rstd * gg[0] + bb[0];
            o[1] = (v[1] - mu) * rstd * gg[1] + bb[1];
            *(f32x2*)&xn[t][2 * lane] = o;
        }
    }

    const int hg = tid & 15, tg1 = tid >> 4;
    const int cg = tid & 31, tg2 = tid >> 5;
    f32x4 acc2[8];
    #pragma unroll
    for (int j = 0; j < 8; j++) acc2[j] = {0.f, 0.f, 0.f, 0.f};

    for (int ci = 0; ci < 8; ++ci) {
        __syncthreads();
        {
            const int r = tid >> 1, kh = (tid & 1) * 64;
            const f32x4* src = (const f32x4*)(w1 + ((size_t)(ci * 64 + r)) * CC + kh);
            #pragma unroll
            for (int i = 0; i < 16; i++) {
                const f32x4 v = src[i];
                const int k = kh + 4 * i;
                wsh[(k + 0) * 64 + r] = v[0];
                wsh[(k + 1) * 64 + r] = v[1];
                wsh[(k + 2) * 64 + r] = v[2];
                wsh[(k + 3) * 64 + r] = v[3];
            }
        }
        __syncthreads();
        f32x4 a1[4];
        {
            const f32x4 bv = *(const f32x4*)(fb1 + ci * 64 + 4 * hg);
            #pragma unroll
            for (int j = 0; j < 4; j++) a1[j] = bv;
        }
        for (int k = 0; k < CC; k += 4) {
            f32x4 xv[4], wv[4];
            #pragma unroll
            for (int j = 0; j < 4; j++) xv[j] = *(const f32x4*)&xn[4 * tg1 + j][k];
            #pragma unroll
            for (int s = 0; s < 4; s++) wv[s] = *(const f32x4*)&wsh[(k + s) * 64 + 4 * hg];
            #pragma unroll
            for (int j = 0; j < 4; j++)
                #pragma unroll
                for (int s = 0; s < 4; s++)
                    #pragma unroll
                    for (int q = 0; q < 4; q++)
                        a1[j][q] += xv[j][s] * wv[s][q];
        }
        #pragma unroll
        for (int j = 0; j < 4; j++) {
            f32x4 ge;
            #pragma unroll
            for (int q = 0; q < 4; q++) {
                const float u = a1[j][q];
                ge[q] = 0.5f * u * (1.f + erff(u * 0.70710678118f));
            }
            *(f32x4*)&gsh[4 * tg1 + j][4 * hg] = ge;
        }
        __syncthreads();
        {
            const int r = tid >> 1, kh = (tid & 1) * 32;
            const f32x4* src = (const f32x4*)(w2 + (size_t)r * HIDDEN + ci * 64 + kh);
            #pragma unroll
            for (int i = 0; i < 8; i++) {
                const f32x4 v = src[i];
                const int k = kh + 4 * i;
                wsh[(k + 0) * CC + r] = v[0];
                wsh[(k + 1) * CC + r] = v[1];
                wsh[(k + 2) * CC + r] = v[2];
                wsh[(k + 3) * CC + r] = v[3];
            }
        }
        __syncthreads();
        for (int k = 0; k < 64; k += 4) {
            f32x4 gv[8], wv[4];
            #pragma unroll
            for (int j = 0; j < 8; j++) gv[j] = *(const f32x4*)&gsh[8 * tg2 + j][k];
            #pragma unroll
            for (int s = 0; s < 4; s++) wv[s] = *(const f32x4*)&wsh[(k + s) * CC + 4 * cg];
            #pragma unroll
            for (int j = 0; j < 8; j++)
                #pragma unroll
                for (int s = 0; s < 4; s++)
                    #pragma unroll
                    for (int q = 0; q < 4; q++)
                        acc2[j][q] += gv[j][s] * wv[s][q];
        }
    }

    const f32x4 bv2 = *(const f32x4*)(fb2 + 4 * cg);
    #pragma unroll
    for (int j = 0; j < 8; j++) {
        const size_t idx = (tok0 + 8 * tg2 + j) * CC + 4 * cg;
        const f32x4 xv = *(const f32x4*)(xio + idx);
        f32x4 o;
        #pragma unroll
        for (int q = 0; q < 4; q++) o[q] = xv[q] + acc2[j][q] + bv2[q];
        *(f32x4*)(xio + idx) = o;
    }
}

extern "C" void kernel_launch(void* const* d_in, const int* in_sizes, int n_in,
                              void* d_out, int out_size, void* d_ws, size_t ws_size,
                              hipStream_t stream) {
    const float* x   = (const float*)d_in[0];
    const float* g1  = (const float*)d_in[1];
    const float* b1  = (const float*)d_in[2];
    const float* sw  = (const float*)d_in[3];
    const float* sb  = (const float*)d_in[4];
    const float* g2  = (const float*)d_in[5];
    const float* b2  = (const float*)d_in[6];
    const float* w1  = (const float*)d_in[7];
    const float* fb1 = (const float*)d_in[8];
    const float* w2  = (const float*)d_in[9];
    const float* fb2 = (const float*)d_in[10];
    float* out = (float*)d_out;

    // Stage A: x2 = x + spatial_mix(LN1(x))  -> stored in d_out
    ka_ln_spatial<<<BATCH * NW * NW, 256, 0, stream>>>(x, g1, b1, sw, sb, out);

    // Stage B: out = x2 + fc2(gelu(fc1(LN2(x2))))  -> in place on d_out
    if (ws_size >= (size_t)524288) {   // need 512 KB packed weights
        unsigned short* wp1 = (unsigned short*)d_ws;   // 131072 shorts (hi+lo)
        unsigned short* wp2 = wp1 + 131072;            // 131072 shorts (hi+lo)
        kprep<<<64, 256, 0, stream>>>(w1, w2, wp1, wp2);
        kb_ln_mlp_mfma<<<(BATCH * LTOK) / 64, 256, 0, stream>>>(out, g2, b2, fb1, fb2, wp1, wp2);
    } else {
        kb_ln_mlp_f32<<<(BATCH * LTOK) / 64, 256, 0, stream>>>(out, g2, b2, w1, fb1, w2, fb2);
    }
}